// Round 1
// baseline (169.155 us; speedup 1.0000x reference)
//
#include <hip/hip_runtime.h>

#define NB 32
#define NS 512
#define ND 768
#define NHEADS 12
#define NTOK 511      // tokens 1..511 (CLS column dropped)
#define NHEAD 250     // head tokens excluding CLS
#define NTAIL 260     // tail tokens
#define CSIZE 53      // tokens per cluster (divisor)

// ---------------- Kernel 1: column sums minus diagonal, fp64 accumulation ----
// grid = 384 heads * 4 row-chunks = 1536 blocks, 256 threads.
// Thread layout: cg = tid&127 -> columns [4cg,4cg+4), rp = tid>>7 -> row parity.
__global__ __launch_bounds__(256) void colsum_kernel(const float* __restrict__ atten,
                                                     double* __restrict__ att) {
    int blk   = blockIdx.x;
    int bh    = blk >> 2;          // 0..383
    int chunk = blk & 3;           // 0..3 (128 rows each)
    int b     = bh / NHEADS;
    int tid   = threadIdx.x;
    int cg    = tid & 127;
    int rp    = tid >> 7;

    const float* base = atten + (size_t)bh * NS * NS;
    double acc0 = 0, acc1 = 0, acc2 = 0, acc3 = 0;
    int r0 = chunk * 128 + rp;
    #pragma unroll 4
    for (int i = 0; i < 64; ++i) {
        int r = r0 + 2 * i;
        const float4 v = *(const float4*)(base + (size_t)r * NS + 4 * cg);
        acc0 += (double)v.x; acc1 += (double)v.y;
        acc2 += (double)v.z; acc3 += (double)v.w;
        if ((r >> 2) == cg) {      // diagonal element (r,r) lives in this float4
            int d = r & 3;         // net out its contribution (colsum - diag)
            if      (d == 0) acc0 -= (double)v.x;
            else if (d == 1) acc1 -= (double)v.y;
            else if (d == 2) acc2 -= (double)v.z;
            else             acc3 -= (double)v.w;
        }
    }
    __shared__ double part[128][4];
    if (rp == 1) { part[cg][0] = acc0; part[cg][1] = acc1;
                   part[cg][2] = acc2; part[cg][3] = acc3; }
    __syncthreads();
    if (rp == 0) {
        acc0 += part[cg][0]; acc1 += part[cg][1];
        acc2 += part[cg][2]; acc3 += part[cg][3];
        double* dst = att + b * NS + 4 * cg;
        atomicAdd(dst + 0, acc0);
        atomicAdd(dst + 1, acc1);
        atomicAdd(dst + 2, acc2);
        atomicAdd(dst + 3, acc3);
    }
}

// ---------------- Kernel 2: rank, select, softmax ----------------------------
// grid = 32 (one block per batch), 512 threads. Thread t handles token t+1.
__global__ __launch_bounds__(512) void rank_kernel(const double* __restrict__ att,
                                                   int* __restrict__ head_tok,
                                                   int* __restrict__ tail_tok,
                                                   float* __restrict__ tail_w) {
    int b = blockIdx.x;
    int t = threadIdx.x;
    __shared__ double v[NTOK];
    __shared__ int    rk[NTOK];
    __shared__ double red[512];

    if (t < NTOK) v[t] = att[b * NS + t + 1] * (1.0 / 12.0);
    __syncthreads();

    int rank = 0;
    if (t < NTOK) {
        double mv = v[t];
        for (int k = 0; k < NTOK; ++k) {
            double vk = v[k];
            rank += (vk > mv) || (vk == mv && k < t);   // jax top_k tie-break
        }
        rk[t] = rank;
    }
    __syncthreads();

    bool isHead = (t < NTOK) && (rank < NHEAD);
    bool isTail = (t < NTOK) && (rank >= NHEAD + 1);    // rank 250 is dropped
    int slot = 0;
    if (isHead) { for (int k = 0; k < t; ++k) slot += (rk[k] < NHEAD); }
    else if (isTail) { for (int k = 0; k < t; ++k) slot += (rk[k] >= NHEAD + 1); }

    // softmax over tail values: max
    red[t] = isTail ? v[t] : -1.0e300;
    __syncthreads();
    for (int off = 256; off > 0; off >>= 1) {
        if (t < off) red[t] = fmax(red[t], red[t + off]);
        __syncthreads();
    }
    double m = red[0];
    __syncthreads();
    // sum of exp
    double e = isTail ? exp(v[t] - m) : 0.0;
    red[t] = e;
    __syncthreads();
    for (int off = 256; off > 0; off >>= 1) {
        if (t < off) red[t] += red[t + off];
        __syncthreads();
    }
    double ssum = red[0];

    if (t == 0) head_tok[b * 256] = 0;                   // CLS
    if (isHead) head_tok[b * 256 + 1 + slot] = t + 1;    // token index into x
    if (isTail) {
        tail_tok[b * 320 + slot] = t + 1;
        tail_w [b * 320 + slot] = (float)(e / ssum);
    }
}

// ---------------- Kernel 3: gather + cluster means ---------------------------
// grid = 32*256 blocks (one output row each), 192 threads (float4 per thread).
__global__ __launch_bounds__(192) void gather_kernel(const float* __restrict__ x,
                                                     const int* __restrict__ head_tok,
                                                     const int* __restrict__ tail_tok,
                                                     const float* __restrict__ tail_w,
                                                     float* __restrict__ out) {
    int blk = blockIdx.x;
    int b   = blk >> 8;
    int p   = blk & 255;
    int c4  = threadIdx.x * 4;
    float4* dst = (float4*)(out + ((size_t)(b * 256 + p)) * ND + c4);

    if (p < NHEAD + 1) {
        int tok = head_tok[b * 256 + p];
        *dst = *(const float4*)(x + ((size_t)(b * NS + tok)) * ND + c4);
    } else {
        int c = p - (NHEAD + 1);
        double a0 = 0, a1 = 0, a2 = 0, a3 = 0;
        int t0 = c * CSIZE;
        int t1 = t0 + CSIZE; if (t1 > NTAIL) t1 = NTAIL;   // last cluster: 48 real rows
        for (int t = t0; t < t1; ++t) {
            float w  = tail_w [b * 320 + t];
            int  tok = tail_tok[b * 320 + t];
            const float4 v = *(const float4*)(x + ((size_t)(b * NS + tok)) * ND + c4);
            a0 += (double)w * v.x; a1 += (double)w * v.y;
            a2 += (double)w * v.z; a3 += (double)w * v.w;
        }
        const double inv = 1.0 / (double)CSIZE;            // mean always divides by 53
        *dst = make_float4((float)(a0 * inv), (float)(a1 * inv),
                           (float)(a2 * inv), (float)(a3 * inv));
    }
}

extern "C" void kernel_launch(void* const* d_in, const int* in_sizes, int n_in,
                              void* d_out, int out_size, void* d_ws, size_t ws_size,
                              hipStream_t stream) {
    const float* x     = (const float*)d_in[0];
    const float* atten = (const float*)d_in[1];
    float* out = (float*)d_out;

    // workspace layout
    double* att      = (double*)d_ws;                               // 32*512*8   = 131072 B
    int*    head_tok = (int*)   ((char*)d_ws + 131072);             // 32*256*4   =  32768 B
    int*    tail_tok = (int*)   ((char*)d_ws + 131072 + 32768);     // 32*320*4   =  40960 B
    float*  tail_w   = (float*) ((char*)d_ws + 131072 + 32768 + 40960);

    hipMemsetAsync(d_ws, 0, 131072, stream);   // zero fp64 accumulators (graph-safe)

    hipLaunchKernelGGL(colsum_kernel, dim3(384 * 4), dim3(256), 0, stream, atten, att);
    hipLaunchKernelGGL(rank_kernel,   dim3(NB),      dim3(512), 0, stream, att,
                       head_tok, tail_tok, tail_w);
    hipLaunchKernelGGL(gather_kernel, dim3(NB * 256), dim3(192), 0, stream, x,
                       head_tok, tail_tok, tail_w, out);
}

// Round 2
// 132.036 us; speedup vs baseline: 1.2811x; 1.2811x over previous
//
#include <hip/hip_runtime.h>

#define NB 32
#define NS 512
#define ND 768
#define NHEADS 12
#define NTOK 511      // tokens 1..511 (CLS column dropped)
#define NHEAD 250     // head tokens excluding CLS
#define NTAIL 260     // tail tokens
#define CSIZE 53      // tokens per cluster (divisor)
#define NCHUNK 4
#define NPART (NB * NHEADS * NCHUNK)   // 1536 partial rows of 512 fp64
#define HEADB 1024    // blocks for the head-copy grid-stride loop

// ---------------- Kernel 1: per-(head,chunk) column sums, fp64, no atomics --
// grid = 1536 blocks (bh*4 + chunk), 256 threads = 4 waves.
// Wave w handles rows {chunk*128 + w + 4i}, lane l covers cols [8l, 8l+8).
// Each wave-iteration streams one full 2 KB row. Diagonal element zeroed.
__global__ __launch_bounds__(256) void colsum_kernel(const float* __restrict__ atten,
                                                     double* __restrict__ partials) {
    int blk   = blockIdx.x;
    int chunk = blk & 3;
    int tid   = threadIdx.x;
    int wave  = tid >> 6, lane = tid & 63;
    const float* base = atten + ((size_t)(blk >> 2)) * NS * NS;

    double a0=0,a1=0,a2=0,a3=0,a4=0,a5=0,a6=0,a7=0;
    #pragma unroll 4
    for (int i = 0; i < 32; ++i) {
        int r = chunk * 128 + wave + 4 * i;
        const float* rp = base + (size_t)r * NS + 8 * lane;
        float4 v0 = *(const float4*)rp;
        float4 v1 = *(const float4*)(rp + 4);
        int d = r - 8 * lane;              // diagonal (r,r) in this lane's span?
        if (d >= 0 && d < 8) {
            switch (d) {                   // compile-time indices only (no scratch)
                case 0: v0.x = 0.f; break;
                case 1: v0.y = 0.f; break;
                case 2: v0.z = 0.f; break;
                case 3: v0.w = 0.f; break;
                case 4: v1.x = 0.f; break;
                case 5: v1.y = 0.f; break;
                case 6: v1.z = 0.f; break;
                default: v1.w = 0.f; break;
            }
        }
        a0 += (double)v0.x; a1 += (double)v0.y; a2 += (double)v0.z; a3 += (double)v0.w;
        a4 += (double)v1.x; a5 += (double)v1.y; a6 += (double)v1.z; a7 += (double)v1.w;
    }

    __shared__ double sh[4 * NS];          // 16 KB
    double* dst = sh + wave * NS + 8 * lane;
    dst[0]=a0; dst[1]=a1; dst[2]=a2; dst[3]=a3;
    dst[4]=a4; dst[5]=a5; dst[6]=a6; dst[7]=a7;
    __syncthreads();
    for (int c = tid; c < NS; c += 256) {
        double s = sh[c] + sh[NS + c] + sh[2 * NS + c] + sh[3 * NS + c];
        partials[(size_t)blk * NS + c] = s;
    }
}

// ---------------- Kernel 2: merge partials, rank, select, softmax ------------
// grid = 32 (one block per batch), 512 threads. Thread t handles token t+1.
__global__ __launch_bounds__(512) void rank_kernel(const double* __restrict__ partials,
                                                   int* __restrict__ head_tok,
                                                   int* __restrict__ tail_tok,
                                                   float* __restrict__ tail_w) {
    int b = blockIdx.x;
    int t = threadIdx.x;
    __shared__ double v[NTOK];
    __shared__ int    rk[NTOK];
    __shared__ double red[512];

    if (t < NTOK) {
        const double* pp = partials + (size_t)b * 48 * NS + (t + 1);
        double s = 0;
        #pragma unroll 8
        for (int p = 0; p < 48; ++p) s += pp[(size_t)p * NS];  // coalesced across t
        v[t] = s * (1.0 / 12.0);
    }
    __syncthreads();

    int rank = 0;
    if (t < NTOK) {
        double mv = v[t];
        for (int k = 0; k < NTOK; ++k) {
            double vk = v[k];
            rank += (vk > mv) || (vk == mv && k < t);   // jax top_k tie-break
        }
        rk[t] = rank;
    }
    __syncthreads();

    bool isHead = (t < NTOK) && (rank < NHEAD);
    bool isTail = (t < NTOK) && (rank >= NHEAD + 1);    // rank 250 is dropped
    int slot = 0;
    if (isHead) { for (int k = 0; k < t; ++k) slot += (rk[k] < NHEAD); }
    else if (isTail) { for (int k = 0; k < t; ++k) slot += (rk[k] >= NHEAD + 1); }

    // softmax over tail values: max
    red[t] = isTail ? v[t] : -1.0e300;
    __syncthreads();
    for (int off = 256; off > 0; off >>= 1) {
        if (t < off) red[t] = fmax(red[t], red[t + off]);
        __syncthreads();
    }
    double m = red[0];
    __syncthreads();
    // sum of exp
    double e = isTail ? exp(v[t] - m) : 0.0;
    red[t] = e;
    __syncthreads();
    for (int off = 256; off > 0; off >>= 1) {
        if (t < off) red[t] += red[t + off];
        __syncthreads();
    }
    double ssum = red[0];

    if (t == 0) head_tok[b * 256] = 0;                   // CLS
    if (isHead) head_tok[b * 256 + 1 + slot] = t + 1;
    if (isTail) {
        tail_tok[b * 320 + slot] = t + 1;
        tail_w [b * 320 + slot] = (float)(e / ssum);
    }
}

// ---------------- Kernel 3: gather + cluster means (one fused kernel) --------
// blocks [0, HEADB): grid-stride float4 copy of the 32*251 head rows.
// blocks [HEADB, HEADB+160): one block per (batch, cluster); (tok,w) preloaded
// into LDS so the 53 x-row gathers pipeline; thread t covers cols t, t+256, t+512.
__global__ __launch_bounds__(256) void gather_kernel(const float* __restrict__ x,
                                                     const int* __restrict__ head_tok,
                                                     const int* __restrict__ tail_tok,
                                                     const float* __restrict__ tail_w,
                                                     float* __restrict__ out) {
    int tid = threadIdx.x;
    if (blockIdx.x < HEADB) {
        const int TOTAL = NB * 251 * 192;                // float4 copies
        for (int f = blockIdx.x * 256 + tid; f < TOTAL; f += HEADB * 256) {
            int rowIdx = f / 192;
            int c4 = (f - rowIdx * 192) * 4;
            int b = rowIdx / 251;
            int p = rowIdx - b * 251;
            int tok = head_tok[b * 256 + p];
            *(float4*)(out + ((size_t)(b * 256 + p)) * ND + c4) =
                *(const float4*)(x + ((size_t)(b * NS + tok)) * ND + c4);
        }
    } else {
        int cb = blockIdx.x - HEADB;
        int b = cb / 5, c = cb - b * 5;
        int t0 = c * CSIZE;
        int cnt = NTAIL - t0 < CSIZE ? NTAIL - t0 : CSIZE;   // 53,53,53,53,48
        __shared__ float wsh[CSIZE];
        __shared__ int   tsh[CSIZE];
        if (tid < cnt) {
            wsh[tid] = tail_w [b * 320 + t0 + tid];
            tsh[tid] = tail_tok[b * 320 + t0 + tid];
        }
        __syncthreads();
        double s0 = 0, s1 = 0, s2 = 0;
        #pragma unroll 4
        for (int k = 0; k < cnt; ++k) {
            float w = wsh[k];
            const float* row = x + ((size_t)(b * NS + tsh[k])) * ND;
            s0 += (double)w * (double)row[tid];
            s1 += (double)w * (double)row[tid + 256];
            s2 += (double)w * (double)row[tid + 512];
        }
        const double inv = 1.0 / (double)CSIZE;          // mean always divides by 53
        float* orow = out + ((size_t)(b * 256 + NHEAD + 1 + c)) * ND;
        orow[tid]       = (float)(s0 * inv);
        orow[tid + 256] = (float)(s1 * inv);
        orow[tid + 512] = (float)(s2 * inv);
    }
}

extern "C" void kernel_launch(void* const* d_in, const int* in_sizes, int n_in,
                              void* d_out, int out_size, void* d_ws, size_t ws_size,
                              hipStream_t stream) {
    const float* x     = (const float*)d_in[0];
    const float* atten = (const float*)d_in[1];
    float* out = (float*)d_out;

    // workspace layout (no zeroing needed — every word is written before read)
    double* partials = (double*)d_ws;                                   // 1536*512*8 = 6291456 B
    int*    head_tok = (int*)   ((char*)d_ws + 6291456);                // 32*256*4
    int*    tail_tok = (int*)   ((char*)d_ws + 6291456 + 32768);        // 32*320*4
    float*  tail_w   = (float*) ((char*)d_ws + 6291456 + 32768 + 40960);

    hipLaunchKernelGGL(colsum_kernel, dim3(NPART),       dim3(256), 0, stream, atten, partials);
    hipLaunchKernelGGL(rank_kernel,   dim3(NB),          dim3(512), 0, stream, partials,
                       head_tok, tail_tok, tail_w);
    hipLaunchKernelGGL(gather_kernel, dim3(HEADB + NB*5), dim3(256), 0, stream, x,
                       head_tok, tail_tok, tail_w, out);
}

// Round 3
// 109.323 us; speedup vs baseline: 1.5473x; 1.2078x over previous
//
#include <hip/hip_runtime.h>

#define NB 32
#define NS 512
#define ND 768
#define NHEADS 12
#define NTOK 511      // tokens 1..511 (CLS column dropped)
#define NHEAD 250     // head tokens excluding CLS
#define NTAIL 260     // tail tokens
#define CSIZE 53      // tokens per cluster (divisor)
#define NPART (NB * NHEADS * 4)        // 1536 partial rows of 512 fp64
#define HEADB 1024    // blocks for the head-copy grid-stride loop

typedef float f4v __attribute__((ext_vector_type(4)));

// ---------------- Kernel 1: per-(head,chunk) column sums, fp64, no atomics --
// grid = 1536 blocks (bh*4 + chunk), 256 threads = 4 waves.
// Wave w handles rows {chunk*128 + w + 4i}, lane l covers cols [8l, 8l+8).
// Streamed once -> nontemporal loads. Diagonal element zeroed in-flight.
__global__ __launch_bounds__(256) void colsum_kernel(const float* __restrict__ atten,
                                                     double* __restrict__ partials) {
    int blk   = blockIdx.x;
    int chunk = blk & 3;
    int tid   = threadIdx.x;
    int wave  = tid >> 6, lane = tid & 63;
    const float* base = atten + ((size_t)(blk >> 2)) * NS * NS;

    double a0=0,a1=0,a2=0,a3=0,a4=0,a5=0,a6=0,a7=0;
    #pragma unroll 4
    for (int i = 0; i < 32; ++i) {
        int r = chunk * 128 + wave + 4 * i;
        const float* rp = base + (size_t)r * NS + 8 * lane;
        f4v v0 = __builtin_nontemporal_load((const f4v*)rp);
        f4v v1 = __builtin_nontemporal_load((const f4v*)(rp + 4));
        int d = r - 8 * lane;              // diagonal (r,r) in this lane's span?
        if (d >= 0 && d < 8) {
            switch (d) {
                case 0: v0.x = 0.f; break;
                case 1: v0.y = 0.f; break;
                case 2: v0.z = 0.f; break;
                case 3: v0.w = 0.f; break;
                case 4: v1.x = 0.f; break;
                case 5: v1.y = 0.f; break;
                case 6: v1.z = 0.f; break;
                default: v1.w = 0.f; break;
            }
        }
        a0 += (double)v0.x; a1 += (double)v0.y; a2 += (double)v0.z; a3 += (double)v0.w;
        a4 += (double)v1.x; a5 += (double)v1.y; a6 += (double)v1.z; a7 += (double)v1.w;
    }

    __shared__ double sh[4 * NS];          // 16 KB
    double* dst = sh + wave * NS + 8 * lane;
    dst[0]=a0; dst[1]=a1; dst[2]=a2; dst[3]=a3;
    dst[4]=a4; dst[5]=a5; dst[6]=a6; dst[7]=a7;
    __syncthreads();
    for (int c = tid; c < NS; c += 256) {
        double s = sh[c] + sh[NS + c] + sh[2 * NS + c] + sh[3 * NS + c];
        partials[(size_t)blk * NS + c] = s;
    }
}

// ---------------- Kernel 2: merge + radix-select + classify + softmax --------
// grid = 32 (one block per batch), 512 threads. Thread t handles token t+1.
// Selection: K = 251st-largest key; head = key>K (+ index-ordered ties),
// the rank-250 token is dropped, rest are tail. Matches jax top_k tie-break.
__global__ __launch_bounds__(512) void rank_kernel(const double* __restrict__ partials,
                                                   int* __restrict__ head_tok,
                                                   int* __restrict__ tail_tok,
                                                   float* __restrict__ tail_w) {
    int b = blockIdx.x;
    int t = threadIdx.x;
    int lane = t & 63, wave = t >> 6;

    __shared__ double v[NTOK];
    __shared__ unsigned int hist[256];
    __shared__ unsigned int gts[8], eqs[8], hs[8], ts[8];
    __shared__ double dred[8];
    __shared__ unsigned long long s_K;
    __shared__ unsigned int s_R, s_byte, s_above;

    bool valid = t < NTOK;
    double val = 0.0;
    unsigned long long key = 0ull;
    if (valid) {
        const double* pp = partials + (size_t)b * 48 * NS + (t + 1);
        double s = 0;
        #pragma unroll 8
        for (int p = 0; p < 48; ++p) s += pp[(size_t)p * NS];  // coalesced across t
        val = s * (1.0 / 12.0);
        v[t] = val;
        long long bits = __double_as_longlong(val);
        key = (bits >= 0) ? ((unsigned long long)bits | 0x8000000000000000ull)
                          : ~((unsigned long long)bits);
    }
    if (t == 0) { s_R = NHEAD + 1; s_K = 0ull; }   // find 251st largest
    __syncthreads();

    // ---- radix select, MSB byte first ----
    for (int pass = 7; pass >= 0; --pass) {
        if (t < 256) hist[t] = 0u;
        __syncthreads();
        if (valid) {
            bool cand = (pass == 7) ||
                ((key >> ((pass + 1) * 8)) == (s_K >> ((pass + 1) * 8)));
            if (cand) atomicAdd(&hist[(unsigned)((key >> (pass * 8)) & 0xFF)], 1u);
        }
        __syncthreads();
        if (wave == 0) {                               // one wave scans 256 bins
            unsigned c0 = hist[4*lane+0], c1 = hist[4*lane+1];
            unsigned c2 = hist[4*lane+2], c3 = hist[4*lane+3];
            unsigned x = c0 + c1 + c2 + c3;
            #pragma unroll
            for (int off = 1; off < 64; off <<= 1) {
                unsigned n = __shfl_up(x, off);
                if (lane >= off) x += n;
            }
            unsigned tot = __shfl(x, 63);
            unsigned aboveLane = tot - x;              // keys in bins > 4*lane+3
            unsigned R = s_R;
            unsigned a3 = aboveLane, a2 = a3 + c3, a1 = a2 + c2, a0 = a1 + c1;
            if (a3 < R && R <= a3 + c3) { s_byte = 4*lane+3; s_above = a3; }
            if (a2 < R && R <= a2 + c2) { s_byte = 4*lane+2; s_above = a2; }
            if (a1 < R && R <= a1 + c1) { s_byte = 4*lane+1; s_above = a1; }
            if (a0 < R && R <= a0 + c0) { s_byte = 4*lane+0; s_above = a0; }
        }
        __syncthreads();
        if (t == 0) {
            s_R -= s_above;
            s_K |= ((unsigned long long)s_byte) << (pass * 8);
        }
        __syncthreads();
    }
    unsigned long long K = s_K;

    // ---- classify (exact tie handling, jax index order) ----
    bool gt = valid && (key > K);
    bool eq = valid && (key == K);
    unsigned long long mgt = __ballot(gt);
    unsigned long long meq = __ballot(eq);
    if (lane == 0) { gts[wave] = __popcll(mgt); eqs[wave] = __popcll(meq); }
    __syncthreads();
    unsigned cntGt = 0;
    #pragma unroll
    for (int w2 = 0; w2 < 8; ++w2) cntGt += gts[w2];
    unsigned eqBefore = __popcll(meq & ((1ull << lane) - 1ull));
    for (int w2 = 0; w2 < wave; ++w2) eqBefore += eqs[w2];
    unsigned rankEq = cntGt + eqBefore;                 // rank if key==K
    bool isHead = gt || (eq && rankEq < NHEAD);
    bool isTail = valid && !gt && !(eq && rankEq <= NHEAD);  // rank==NHEAD dropped

    // ---- slots via ballot prefix sums ----
    unsigned long long mh = __ballot(isHead);
    unsigned long long mt = __ballot(isTail);
    if (lane == 0) { hs[wave] = __popcll(mh); ts[wave] = __popcll(mt); }
    __syncthreads();
    unsigned hslot = __popcll(mh & ((1ull << lane) - 1ull));
    unsigned tslot = __popcll(mt & ((1ull << lane) - 1ull));
    for (int w2 = 0; w2 < wave; ++w2) { hslot += hs[w2]; tslot += ts[w2]; }

    // ---- softmax over tail values (wave shfl reduce + 8-way combine) ----
    double tv = isTail ? val : -1.0e300;
    #pragma unroll
    for (int off = 32; off; off >>= 1) tv = fmax(tv, __shfl_xor(tv, off));
    if (lane == 0) dred[wave] = tv;
    __syncthreads();
    double m = dred[0];
    #pragma unroll
    for (int w2 = 1; w2 < 8; ++w2) m = fmax(m, dred[w2]);
    double e = isTail ? exp(val - m) : 0.0;
    double se = e;
    #pragma unroll
    for (int off = 32; off; off >>= 1) se += __shfl_xor(se, off);
    __syncthreads();                                    // dred reuse
    if (lane == 0) dred[wave] = se;
    __syncthreads();
    double ssum = 0;
    #pragma unroll
    for (int w2 = 0; w2 < 8; ++w2) ssum += dred[w2];

    if (t == 0) head_tok[b * 256] = 0;                   // CLS
    if (isHead) head_tok[b * 256 + 1 + hslot] = t + 1;
    if (isTail) {
        tail_tok[b * 320 + tslot] = t + 1;
        tail_w [b * 320 + tslot] = (float)(e / ssum);
    }
}

// ---------------- Kernel 3: gather + cluster means (one fused kernel) --------
// blocks [0, HEADB): grid-stride float4 copy of the 32*251 head rows.
// blocks [HEADB, HEADB+160): one block per (batch, cluster); (tok,w) in LDS,
// thread t covers cols t, t+256, t+512. x rows touched once -> nt loads/stores.
__global__ __launch_bounds__(256) void gather_kernel(const float* __restrict__ x,
                                                     const int* __restrict__ head_tok,
                                                     const int* __restrict__ tail_tok,
                                                     const float* __restrict__ tail_w,
                                                     float* __restrict__ out) {
    int tid = threadIdx.x;
    if (blockIdx.x < HEADB) {
        const int TOTAL = NB * 251 * 192;                // float4 copies
        for (int f = blockIdx.x * 256 + tid; f < TOTAL; f += HEADB * 256) {
            int rowIdx = f / 192;
            int c4 = (f - rowIdx * 192) * 4;
            int b = rowIdx / 251;
            int p = rowIdx - b * 251;
            int tok = head_tok[b * 256 + p];
            f4v vv = __builtin_nontemporal_load(
                (const f4v*)(x + ((size_t)(b * NS + tok)) * ND + c4));
            __builtin_nontemporal_store(vv,
                (f4v*)(out + ((size_t)(b * 256 + p)) * ND + c4));
        }
    } else {
        int cb = blockIdx.x - HEADB;
        int b = cb / 5, c = cb - b * 5;
        int t0 = c * CSIZE;
        int cnt = NTAIL - t0 < CSIZE ? NTAIL - t0 : CSIZE;   // 53,53,53,53,48
        __shared__ float wsh[CSIZE];
        __shared__ int   tsh[CSIZE];
        if (tid < cnt) {
            wsh[tid] = tail_w [b * 320 + t0 + tid];
            tsh[tid] = tail_tok[b * 320 + t0 + tid];
        }
        __syncthreads();
        double s0 = 0, s1 = 0, s2 = 0;
        #pragma unroll 4
        for (int k = 0; k < cnt; ++k) {
            float w = wsh[k];
            const float* row = x + ((size_t)(b * NS + tsh[k])) * ND;
            s0 += (double)w * (double)__builtin_nontemporal_load(row + tid);
            s1 += (double)w * (double)__builtin_nontemporal_load(row + tid + 256);
            s2 += (double)w * (double)__builtin_nontemporal_load(row + tid + 512);
        }
        const double inv = 1.0 / (double)CSIZE;          // mean always divides by 53
        float* orow = out + ((size_t)(b * 256 + NHEAD + 1 + c)) * ND;
        __builtin_nontemporal_store((float)(s0 * inv), orow + tid);
        __builtin_nontemporal_store((float)(s1 * inv), orow + tid + 256);
        __builtin_nontemporal_store((float)(s2 * inv), orow + tid + 512);
    }
}

extern "C" void kernel_launch(void* const* d_in, const int* in_sizes, int n_in,
                              void* d_out, int out_size, void* d_ws, size_t ws_size,
                              hipStream_t stream) {
    const float* x     = (const float*)d_in[0];
    const float* atten = (const float*)d_in[1];
    float* out = (float*)d_out;

    // workspace layout (no zeroing needed — every word is written before read)
    double* partials = (double*)d_ws;                                   // 1536*512*8 = 6291456 B
    int*    head_tok = (int*)   ((char*)d_ws + 6291456);                // 32*256*4
    int*    tail_tok = (int*)   ((char*)d_ws + 6291456 + 32768);        // 32*320*4
    float*  tail_w   = (float*) ((char*)d_ws + 6291456 + 32768 + 40960);

    hipLaunchKernelGGL(colsum_kernel, dim3(NPART),        dim3(256), 0, stream, atten, partials);
    hipLaunchKernelGGL(rank_kernel,   dim3(NB),           dim3(512), 0, stream, partials,
                       head_tok, tail_tok, tail_w);
    hipLaunchKernelGGL(gather_kernel, dim3(HEADB + NB*5), dim3(256), 0, stream, x,
                       head_tok, tail_tok, tail_w, out);
}

// Round 4
// 98.122 us; speedup vs baseline: 1.7239x; 1.1142x over previous
//
#include <hip/hip_runtime.h>

#define NB 32
#define NS 512
#define ND 768
#define NHEADS 12
#define NTOK 511      // tokens 1..511 (CLS column dropped)
#define NHEAD 250     // head tokens excluding CLS
#define NTAIL 260     // tail tokens
#define CSIZE 53      // tokens per cluster (divisor)
#define NPART (NB * NHEADS * 4)        // 1536 partial rows of 512 fp64
#define HEADB 1024    // blocks for the head-copy grid-stride loop

typedef float f4v __attribute__((ext_vector_type(4)));

// ---------------- Kernel 1: per-(head,chunk) column sums, fp64, no atomics --
// grid = 1536 blocks (bh*4 + chunk), 256 threads = 4 waves.
// Wave w handles rows {chunk*128 + w + 4i}. Lane l loads float4 at col 4l
// (bytes 0..1023 of the row, contiguous 16B/lane) and at col 256+4l
// (bytes 1024..2047) — every load instruction is perfectly coalesced.
// Diagonal element zeroed in whichever load covers it (uniform on chunk).
__global__ __launch_bounds__(256) void colsum_kernel(const float* __restrict__ atten,
                                                     double* __restrict__ partials) {
    int blk   = blockIdx.x;
    int chunk = blk & 3;
    int tid   = threadIdx.x;
    int wave  = tid >> 6, lane = tid & 63;
    const float* base = atten + ((size_t)(blk >> 2)) * NS * NS;

    double a0=0,a1=0,a2=0,a3=0,a4=0,a5=0,a6=0,a7=0;
    #pragma unroll 8
    for (int i = 0; i < 32; ++i) {
        int r = chunk * 128 + wave + 4 * i;
        const float* row = base + (size_t)r * NS;
        f4v v0 = __builtin_nontemporal_load((const f4v*)(row + 4 * lane));        // cols [4l,4l+4)
        f4v v1 = __builtin_nontemporal_load((const f4v*)(row + 256 + 4 * lane));  // cols [256+4l,..)
        if (chunk < 2) {                       // diag col r in [0,256) -> v0
            int d = r - 4 * lane;
            if (d >= 0 && d < 4) {
                switch (d) {
                    case 0: v0.x = 0.f; break;
                    case 1: v0.y = 0.f; break;
                    case 2: v0.z = 0.f; break;
                    default: v0.w = 0.f; break;
                }
            }
        } else {                               // diag col r in [256,512) -> v1
            int d = (r - 256) - 4 * lane;
            if (d >= 0 && d < 4) {
                switch (d) {
                    case 0: v1.x = 0.f; break;
                    case 1: v1.y = 0.f; break;
                    case 2: v1.z = 0.f; break;
                    default: v1.w = 0.f; break;
                }
            }
        }
        a0 += (double)v0.x; a1 += (double)v0.y; a2 += (double)v0.z; a3 += (double)v0.w;
        a4 += (double)v1.x; a5 += (double)v1.y; a6 += (double)v1.z; a7 += (double)v1.w;
    }

    __shared__ double sh[4 * NS];              // 16 KB
    {
        double* d0 = sh + wave * NS + 4 * lane;        // cols 4l..4l+3
        d0[0]=a0; d0[1]=a1; d0[2]=a2; d0[3]=a3;
        double* d1 = sh + wave * NS + 256 + 4 * lane;  // cols 256+4l..
        d1[0]=a4; d1[1]=a5; d1[2]=a6; d1[3]=a7;
    }
    __syncthreads();
    for (int c = tid; c < NS; c += 256) {
        double s = sh[c] + sh[NS + c] + sh[2 * NS + c] + sh[3 * NS + c];
        partials[(size_t)blk * NS + c] = s;
    }
}

// ---------------- Kernel 2: merge + radix-select + classify + softmax --------
// grid = 32 (one block per batch), 512 threads. Thread t handles token t+1.
// Selection: K = 251st-largest key; head = key>K (+ index-ordered ties),
// the rank-250 token is dropped, rest are tail. Matches jax top_k tie-break.
__global__ __launch_bounds__(512) void rank_kernel(const double* __restrict__ partials,
                                                   int* __restrict__ head_tok,
                                                   int* __restrict__ tail_tok,
                                                   float* __restrict__ tail_w) {
    int b = blockIdx.x;
    int t = threadIdx.x;
    int lane = t & 63, wave = t >> 6;

    __shared__ unsigned int hist[256];
    __shared__ unsigned int gts[8], eqs[8], hs[8], ts[8];
    __shared__ double dred[8];
    __shared__ unsigned long long s_K;
    __shared__ unsigned int s_R, s_byte, s_above;

    bool valid = t < NTOK;
    double val = 0.0;
    unsigned long long key = 0ull;
    if (valid) {
        const double* pp = partials + (size_t)b * 48 * NS + (t + 1);
        double s = 0;
        #pragma unroll 8
        for (int p = 0; p < 48; ++p) s += pp[(size_t)p * NS];  // coalesced across t
        val = s * (1.0 / 12.0);
        long long bits = __double_as_longlong(val);
        key = (bits >= 0) ? ((unsigned long long)bits | 0x8000000000000000ull)
                          : ~((unsigned long long)bits);
    }
    if (t == 0) { s_R = NHEAD + 1; s_K = 0ull; }   // find 251st largest
    __syncthreads();

    // ---- radix select, MSB byte first ----
    for (int pass = 7; pass >= 0; --pass) {
        if (t < 256) hist[t] = 0u;
        __syncthreads();
        if (valid) {
            bool cand = (pass == 7) ||
                ((key >> ((pass + 1) * 8)) == (s_K >> ((pass + 1) * 8)));
            if (cand) atomicAdd(&hist[(unsigned)((key >> (pass * 8)) & 0xFF)], 1u);
        }
        __syncthreads();
        if (wave == 0) {                               // one wave scans 256 bins
            unsigned c0 = hist[4*lane+0], c1 = hist[4*lane+1];
            unsigned c2 = hist[4*lane+2], c3 = hist[4*lane+3];
            unsigned x = c0 + c1 + c2 + c3;
            #pragma unroll
            for (int off = 1; off < 64; off <<= 1) {
                unsigned n = __shfl_up(x, off);
                if (lane >= off) x += n;
            }
            unsigned tot = __shfl(x, 63);
            unsigned aboveLane = tot - x;              // keys in bins > 4*lane+3
            unsigned R = s_R;
            unsigned a3 = aboveLane, a2 = a3 + c3, a1 = a2 + c2, a0 = a1 + c1;
            if (a3 < R && R <= a3 + c3) { s_byte = 4*lane+3; s_above = a3; }
            if (a2 < R && R <= a2 + c2) { s_byte = 4*lane+2; s_above = a2; }
            if (a1 < R && R <= a1 + c1) { s_byte = 4*lane+1; s_above = a1; }
            if (a0 < R && R <= a0 + c0) { s_byte = 4*lane+0; s_above = a0; }
        }
        __syncthreads();
        if (t == 0) {
            s_R -= s_above;
            s_K |= ((unsigned long long)s_byte) << (pass * 8);
        }
        __syncthreads();
    }
    unsigned long long K = s_K;

    // ---- classify (exact tie handling, jax index order) ----
    bool gt = valid && (key > K);
    bool eq = valid && (key == K);
    unsigned long long mgt = __ballot(gt);
    unsigned long long meq = __ballot(eq);
    if (lane == 0) { gts[wave] = __popcll(mgt); eqs[wave] = __popcll(meq); }
    __syncthreads();
    unsigned cntGt = 0;
    #pragma unroll
    for (int w2 = 0; w2 < 8; ++w2) cntGt += gts[w2];
    unsigned eqBefore = __popcll(meq & ((1ull << lane) - 1ull));
    for (int w2 = 0; w2 < wave; ++w2) eqBefore += eqs[w2];
    unsigned rankEq = cntGt + eqBefore;                 // rank if key==K
    bool isHead = gt || (eq && rankEq < NHEAD);
    bool isTail = valid && !gt && !(eq && rankEq <= NHEAD);  // rank==NHEAD dropped

    // ---- slots via ballot prefix sums ----
    unsigned long long mh = __ballot(isHead);
    unsigned long long mt = __ballot(isTail);
    if (lane == 0) { hs[wave] = __popcll(mh); ts[wave] = __popcll(mt); }
    __syncthreads();
    unsigned hslot = __popcll(mh & ((1ull << lane) - 1ull));
    unsigned tslot = __popcll(mt & ((1ull << lane) - 1ull));
    for (int w2 = 0; w2 < wave; ++w2) { hslot += hs[w2]; tslot += ts[w2]; }

    // ---- softmax over tail values (wave shfl reduce + 8-way combine) ----
    double tv = isTail ? val : -1.0e300;
    #pragma unroll
    for (int off = 32; off; off >>= 1) tv = fmax(tv, __shfl_xor(tv, off));
    if (lane == 0) dred[wave] = tv;
    __syncthreads();
    double m = dred[0];
    #pragma unroll
    for (int w2 = 1; w2 < 8; ++w2) m = fmax(m, dred[w2]);
    double e = isTail ? exp(val - m) : 0.0;
    double se = e;
    #pragma unroll
    for (int off = 32; off; off >>= 1) se += __shfl_xor(se, off);
    __syncthreads();                                    // dred reuse
    if (lane == 0) dred[wave] = se;
    __syncthreads();
    double ssum = 0;
    #pragma unroll
    for (int w2 = 0; w2 < 8; ++w2) ssum += dred[w2];

    if (t == 0) head_tok[b * 256] = 0;                   // CLS
    if (isHead) head_tok[b * 256 + 1 + hslot] = t + 1;
    if (isTail) {
        tail_tok[b * 320 + tslot] = t + 1;
        tail_w [b * 320 + tslot] = (float)(e / ssum);
    }
}

// ---------------- Kernel 3: gather + cluster means (one fused kernel) --------
// blocks [0, HEADB): grid-stride float4 copy of the 32*251 head rows.
// blocks [HEADB, HEADB+160): one block per (batch, cluster); (tok,w) in LDS,
// thread t<192 owns float4 at col 4t (16B/lane, fully coalesced).
// x loads are cached (x fits L3 and is reused); out stores nontemporal.
__global__ __launch_bounds__(256) void gather_kernel(const float* __restrict__ x,
                                                     const int* __restrict__ head_tok,
                                                     const int* __restrict__ tail_tok,
                                                     const float* __restrict__ tail_w,
                                                     float* __restrict__ out) {
    int tid = threadIdx.x;
    if (blockIdx.x < HEADB) {
        const int TOTAL = NB * 251 * 192;                // float4 copies
        for (int f = blockIdx.x * 256 + tid; f < TOTAL; f += HEADB * 256) {
            int rowIdx = f / 192;
            int c4 = (f - rowIdx * 192) * 4;
            int b = rowIdx / 251;
            int p = rowIdx - b * 251;
            int tok = head_tok[b * 256 + p];
            f4v vv = *(const f4v*)(x + ((size_t)(b * NS + tok)) * ND + c4);
            __builtin_nontemporal_store(vv,
                (f4v*)(out + ((size_t)(b * 256 + p)) * ND + c4));
        }
    } else {
        int cb = blockIdx.x - HEADB;
        int b = cb / 5, c = cb - b * 5;
        int t0 = c * CSIZE;
        int cnt = NTAIL - t0 < CSIZE ? NTAIL - t0 : CSIZE;   // 53,53,53,53,48
        __shared__ float wsh[CSIZE];
        __shared__ int   tsh[CSIZE];
        if (tid < cnt) {
            wsh[tid] = tail_w [b * 320 + t0 + tid];
            tsh[tid] = tail_tok[b * 320 + t0 + tid];
        }
        __syncthreads();
        if (tid < 192) {
            double s0 = 0, s1 = 0, s2 = 0, s3 = 0;
            #pragma unroll 4
            for (int k = 0; k < cnt; ++k) {
                float w = wsh[k];
                const f4v v = *(const f4v*)(x + ((size_t)(b * NS + tsh[k])) * ND + 4 * tid);
                s0 += (double)w * (double)v.x;
                s1 += (double)w * (double)v.y;
                s2 += (double)w * (double)v.z;
                s3 += (double)w * (double)v.w;
            }
            const double inv = 1.0 / (double)CSIZE;      // mean always divides by 53
            f4v r;
            r.x = (float)(s0 * inv); r.y = (float)(s1 * inv);
            r.z = (float)(s2 * inv); r.w = (float)(s3 * inv);
            __builtin_nontemporal_store(r,
                (f4v*)(out + ((size_t)(b * 256 + NHEAD + 1 + c)) * ND + 4 * tid));
        }
    }
}

extern "C" void kernel_launch(void* const* d_in, const int* in_sizes, int n_in,
                              void* d_out, int out_size, void* d_ws, size_t ws_size,
                              hipStream_t stream) {
    const float* x     = (const float*)d_in[0];
    const float* atten = (const float*)d_in[1];
    float* out = (float*)d_out;

    // workspace layout (no zeroing needed — every word is written before read)
    double* partials = (double*)d_ws;                                   // 1536*512*8 = 6291456 B
    int*    head_tok = (int*)   ((char*)d_ws + 6291456);                // 32*256*4
    int*    tail_tok = (int*)   ((char*)d_ws + 6291456 + 32768);        // 32*320*4
    float*  tail_w   = (float*) ((char*)d_ws + 6291456 + 32768 + 40960);

    hipLaunchKernelGGL(colsum_kernel, dim3(NPART),        dim3(256), 0, stream, atten, partials);
    hipLaunchKernelGGL(rank_kernel,   dim3(NB),           dim3(512), 0, stream, partials,
                       head_tok, tail_tok, tail_w);
    hipLaunchKernelGGL(gather_kernel, dim3(HEADB + NB*5), dim3(256), 0, stream, x,
                       head_tok, tail_tok, tail_w, out);
}